// Round 5
// baseline (344.744 us; speedup 1.0000x reference)
//
#include <hip/hip_runtime.h>
#include <hip/hip_cooperative_groups.h>
#include <math.h>

namespace cg = cooperative_groups;

#define D      128
#define D4     32          // D in float4 units
#define NTREE  256
#define NL1    65536
#define EPSBN  1e-5f

// ---- workspace layout (in floats) ----
#define G0_OFF 0L                       // [256][128] tree-sum of x
#define P2_OFF 32768L                   // [256][128] p2 == g1
#define SA_OFF 65536L                   // statsA: sum[128], sumsq[128]
#define SB_OFF 65792L
#define SC_OFF 66048L
#define SD_OFF 66304L
#define T2_OFF 66560L                   // [256][128] t2, then u2 in-place
#define ZERO_CNT 66560                  // g0+p2+4 stats blocks, contiguous
#define T1F_OFF 131072L                 // fallback path only: [NL1][D] t1/u

// NOTE: macro params must not be named x/y/z/w (member-token substitution).
#define FMA4(A_, S_, W_) { (A_).x = fmaf((S_),(W_).x,(A_).x); (A_).y = fmaf((S_),(W_).y,(A_).y); \
                           (A_).z = fmaf((S_),(W_).z,(A_).z); (A_).w = fmaf((S_),(W_).w,(A_).w); }
#define ADD4(A_, B_)     { (A_).x += (B_).x; (A_).y += (B_).y; (A_).z += (B_).z; (A_).w += (B_).w; }
#define F4Z              make_float4(0.f,0.f,0.f,0.f)

__global__ __launch_bounds__(256) void k_zero(float* __restrict__ ws) {
    int i = blockIdx.x * 256 + threadIdx.x;
    if (i < ZERO_CNT) ws[i] = 0.f;
}

// 128-row-tile matmul: acc[8] covers rows tr*8..tr*8+7, cols tc*4..tc*4+3
__device__ __forceinline__ void mm128(const float (*tile)[D], const float* __restrict__ w,
                                      float4 bb, int tr, int tc, float4 acc[8])
{
    const float4* __restrict__ wv = (const float4*)w;
    #pragma unroll
    for (int r = 0; r < 8; ++r) acc[r] = bb;
    #pragma unroll 2
    for (int k4 = 0; k4 < 32; ++k4) {
        float4 wr0 = wv[(k4*4+0)*D4 + tc];
        float4 wr1 = wv[(k4*4+1)*D4 + tc];
        float4 wr2 = wv[(k4*4+2)*D4 + tc];
        float4 wr3 = wv[(k4*4+3)*D4 + tc];
        #pragma unroll
        for (int r = 0; r < 8; ++r) {
            float4 a4 = *(const float4*)&tile[tr*8 + r][k4*4];
            FMA4(acc[r], a4.x, wr0) FMA4(acc[r], a4.y, wr1)
            FMA4(acc[r], a4.z, wr2) FMA4(acc[r], a4.w, wr3)
        }
    }
}

// ============================================================================
// Fused layer-1 pipeline (cooperative, persistent). 256 blocks x 512 threads,
// 1 block/CU guaranteed co-resident (64 KB LDS). Block b owns tree b: two
// sequential 128-row tiles. t1/u live in registers (accA/accB, 8 float4 each).
// ============================================================================
__global__ __launch_bounds__(512, 2) void k_fused(
        const float* __restrict__ x,
        const float* __restrict__ w1, const float* __restrict__ b1,
        const float* __restrict__ mg, const float* __restrict__ mbe,   // mlp1 inner bn
        const float* __restrict__ w2, const float* __restrict__ b2,
        const float* __restrict__ bg, const float* __restrict__ bb_,   // bn1 outer
        float* __restrict__ g0, float* __restrict__ p2,
        float* __restrict__ statsA, float* __restrict__ statsB)
{
    __shared__ __align__(16) float tile[128][D];   // 64 KB
    cg::grid_group grid = cg::this_grid();

    const int t  = threadIdx.x;
    const int b  = blockIdx.x;       // == tree id
    const int tc = t & 31;
    const int tr = t >> 5;           // 0..15
    const long rowbase = (long)b * 256;

    float4 accA[8], accB[8];
    float4 gacc = F4Z;
    const float4* __restrict__ x4 = (const float4*)x;
    const float4 bb1 = ((const float4*)b1)[tc];
    const float4 bb2 = ((const float4*)b2)[tc];

    // ---------------- phase 1: p1 tiles -> t1 (regs); g0; statsA ----------------
    // tile A (rows rowbase .. rowbase+127)
    #pragma unroll
    for (int s = 0; s < 8; ++s) {
        const int r = tr * 8 + s;
        const long leaf0 = (rowbase + r) * 16;
        float4 a = F4Z;
        #pragma unroll
        for (int l = 0; l < 16; ++l) { float4 v = x4[(leaf0 + l)*D4 + tc]; ADD4(a, v) }
        *(float4*)&tile[r][tc*4] = a;
        ADD4(gacc, a)
    }
    __syncthreads();
    mm128(tile, w1, bb1, tr, tc, accA);
    __syncthreads();                 // done reading tile A
    // tile B (rows rowbase+128 .. rowbase+255)
    #pragma unroll
    for (int s = 0; s < 8; ++s) {
        const int r = tr * 8 + s;
        const long leaf0 = (rowbase + 128 + r) * 16;
        float4 a = F4Z;
        #pragma unroll
        for (int l = 0; l < 16; ++l) { float4 v = x4[(leaf0 + l)*D4 + tc]; ADD4(a, v) }
        *(float4*)&tile[r][tc*4] = a;
        ADD4(gacc, a)
    }
    __syncthreads();
    mm128(tile, w1, bb1, tr, tc, accB);

    // stats over both tiles + g0
    {
        float4 s4 = F4Z, q4 = F4Z;
        #pragma unroll
        for (int r = 0; r < 8; ++r) {
            ADD4(s4, accA[r])
            q4.x = fmaf(accA[r].x, accA[r].x, q4.x); q4.y = fmaf(accA[r].y, accA[r].y, q4.y);
            q4.z = fmaf(accA[r].z, accA[r].z, q4.z); q4.w = fmaf(accA[r].w, accA[r].w, q4.w);
            ADD4(s4, accB[r])
            q4.x = fmaf(accB[r].x, accB[r].x, q4.x); q4.y = fmaf(accB[r].y, accB[r].y, q4.y);
            q4.z = fmaf(accB[r].z, accB[r].z, q4.z); q4.w = fmaf(accB[r].w, accB[r].w, q4.w);
        }
        __syncthreads();             // done reading tile B
        *(float4*)&tile[tr     ][tc*4] = s4;
        *(float4*)&tile[16 + tr][tc*4] = q4;
        *(float4*)&tile[32 + tr][tc*4] = gacc;
        __syncthreads();
        if (t < 32) {
            float4 S = F4Z, Q = F4Z;
            #pragma unroll
            for (int g = 0; g < 16; ++g) {
                float4 vs = *(const float4*)&tile[g][t*4];      ADD4(S, vs)
                float4 vq = *(const float4*)&tile[16 + g][t*4]; ADD4(Q, vq)
            }
            atomicAdd(&statsA[t*4+0], S.x); atomicAdd(&statsA[t*4+1], S.y);
            atomicAdd(&statsA[t*4+2], S.z); atomicAdd(&statsA[t*4+3], S.w);
            atomicAdd(&statsA[D + t*4+0], Q.x); atomicAdd(&statsA[D + t*4+1], Q.y);
            atomicAdd(&statsA[D + t*4+2], Q.z); atomicAdd(&statsA[D + t*4+3], Q.w);
        } else if (t < 64) {
            const int c = t - 32;
            float4 G = F4Z;
            #pragma unroll
            for (int g = 0; g < 16; ++g) { float4 vg = *(const float4*)&tile[32 + g][c*4]; ADD4(G, vg) }
            *(float4*)&g0[b*D + c*4] = G;     // block owns tree b exclusively
        }
    }
    __threadfence();
    grid.sync();

    // ---------------- phase 2: y = relu(bn_inner(t1)); u = y@w2+b2 ----------------
    float4 scv, shv;
    {
        const float inv = 1.f / (float)NL1;
        #pragma unroll
        for (int i = 0; i < 4; ++i) {
            const int c = tc*4 + i;
            float m  = statsA[c] * inv;
            float vv = statsA[D + c] * inv - m * m;
            float rs = rsqrtf(vv + EPSBN);
            float sc = mg[c] * rs;
            ((float*)&scv)[i] = sc;
            ((float*)&shv)[i] = mbe[c] - m * sc;
        }
    }
    // tile A
    #pragma unroll
    for (int r = 0; r < 8; ++r) {
        float4 y;
        y.x = fmaxf(fmaf(accA[r].x, scv.x, shv.x), 0.f);
        y.y = fmaxf(fmaf(accA[r].y, scv.y, shv.y), 0.f);
        y.z = fmaxf(fmaf(accA[r].z, scv.z, shv.z), 0.f);
        y.w = fmaxf(fmaf(accA[r].w, scv.w, shv.w), 0.f);
        *(float4*)&tile[tr*8 + r][tc*4] = y;
    }
    __syncthreads();
    mm128(tile, w2, bb2, tr, tc, accA);
    __syncthreads();
    // tile B
    #pragma unroll
    for (int r = 0; r < 8; ++r) {
        float4 y;
        y.x = fmaxf(fmaf(accB[r].x, scv.x, shv.x), 0.f);
        y.y = fmaxf(fmaf(accB[r].y, scv.y, shv.y), 0.f);
        y.z = fmaxf(fmaf(accB[r].z, scv.z, shv.z), 0.f);
        y.w = fmaxf(fmaf(accB[r].w, scv.w, shv.w), 0.f);
        *(float4*)&tile[tr*8 + r][tc*4] = y;
    }
    __syncthreads();
    mm128(tile, w2, bb2, tr, tc, accB);

    // statsB over u (both tiles)
    {
        float4 s4 = F4Z, q4 = F4Z;
        #pragma unroll
        for (int r = 0; r < 8; ++r) {
            ADD4(s4, accA[r])
            q4.x = fmaf(accA[r].x, accA[r].x, q4.x); q4.y = fmaf(accA[r].y, accA[r].y, q4.y);
            q4.z = fmaf(accA[r].z, accA[r].z, q4.z); q4.w = fmaf(accA[r].w, accA[r].w, q4.w);
            ADD4(s4, accB[r])
            q4.x = fmaf(accB[r].x, accB[r].x, q4.x); q4.y = fmaf(accB[r].y, accB[r].y, q4.y);
            q4.z = fmaf(accB[r].z, accB[r].z, q4.z); q4.w = fmaf(accB[r].w, accB[r].w, q4.w);
        }
        __syncthreads();             // done reading tile (y_B)
        *(float4*)&tile[tr     ][tc*4] = s4;
        *(float4*)&tile[16 + tr][tc*4] = q4;
        __syncthreads();
        if (t < 32) {
            float4 S = F4Z, Q = F4Z;
            #pragma unroll
            for (int g = 0; g < 16; ++g) {
                float4 vs = *(const float4*)&tile[g][t*4];      ADD4(S, vs)
                float4 vq = *(const float4*)&tile[16 + g][t*4]; ADD4(Q, vq)
            }
            atomicAdd(&statsB[t*4+0], S.x); atomicAdd(&statsB[t*4+1], S.y);
            atomicAdd(&statsB[t*4+2], S.z); atomicAdd(&statsB[t*4+3], S.w);
            atomicAdd(&statsB[D + t*4+0], Q.x); atomicAdd(&statsB[D + t*4+1], Q.y);
            atomicAdd(&statsB[D + t*4+2], Q.z); atomicAdd(&statsB[D + t*4+3], Q.w);
        }
    }
    __threadfence();
    grid.sync();

    // ---------------- phase 3: h1 = relu(bn_outer(u)); pool -> p2[tree] ----------------
    {
        const float inv = 1.f / (float)NL1;
        #pragma unroll
        for (int i = 0; i < 4; ++i) {
            const int c = tc*4 + i;
            float m  = statsB[c] * inv;
            float vv = statsB[D + c] * inv - m * m;
            float rs = rsqrtf(vv + EPSBN);
            float sc = bg[c] * rs;
            ((float*)&scv)[i] = sc;
            ((float*)&shv)[i] = bb_[c] - m * sc;
        }
        float4 psum = F4Z;
        #pragma unroll
        for (int r = 0; r < 8; ++r) {
            psum.x += fmaxf(fmaf(accA[r].x, scv.x, shv.x), 0.f);
            psum.y += fmaxf(fmaf(accA[r].y, scv.y, shv.y), 0.f);
            psum.z += fmaxf(fmaf(accA[r].z, scv.z, shv.z), 0.f);
            psum.w += fmaxf(fmaf(accA[r].w, scv.w, shv.w), 0.f);
            psum.x += fmaxf(fmaf(accB[r].x, scv.x, shv.x), 0.f);
            psum.y += fmaxf(fmaf(accB[r].y, scv.y, shv.y), 0.f);
            psum.z += fmaxf(fmaf(accB[r].z, scv.z, shv.z), 0.f);
            psum.w += fmaxf(fmaf(accB[r].w, scv.w, shv.w), 0.f);
        }
        __syncthreads();
        *(float4*)&tile[tr][tc*4] = psum;
        __syncthreads();
        if (t < 32) {
            float4 S = F4Z;
            #pragma unroll
            for (int g = 0; g < 16; ++g) { float4 vs = *(const float4*)&tile[g][t*4]; ADD4(S, vs) }
            *(float4*)&p2[b*D + t*4] = S;
        }
    }
}

// ===================== fallback path (proven R3 kernels) =====================
__global__ __launch_bounds__(256) void k_leafF(const float* __restrict__ x,
        const float* __restrict__ w1, const float* __restrict__ b1,
        float* __restrict__ t1, float* __restrict__ g0, float* __restrict__ statsA)
{
    __shared__ __align__(16) float p1s[32][D];
    __shared__ __align__(16) float red[2][8][D];
    const int t = threadIdx.x;
    const int b = blockIdx.x;
    const int j4 = t & 31, pr = t >> 5;
    const float4* __restrict__ x4 = (const float4*)x;

    float4 gacc = F4Z;
    #pragma unroll
    for (int io = 0; io < 4; ++io) {
        int pp = pr + io * 8;
        int Rleaf = (b * 32 + pp) * 16;
        float4 a = F4Z;
        #pragma unroll
        for (int l = 0; l < 16; ++l) { float4 v = x4[(Rleaf + l) * D4 + j4]; ADD4(a, v) }
        *(float4*)&p1s[pp][j4*4] = a;
        ADD4(gacc, a)
    }
    *(float4*)&red[0][pr][j4*4] = gacc;
    __syncthreads();
    if (t < D) {
        float s = 0.f;
        #pragma unroll
        for (int g = 0; g < 8; ++g) s += red[0][g][t];
        atomicAdd(&g0[(b >> 3) * D + t], s);
    }
    __syncthreads();

    const int tc = t & 31, tr = t >> 5;
    float4 acc[8];  // only 4 used per row-group here; reuse mm128 on 32-row tile manually
    // 32x128 tile mm: 4 rows x 4 cols per thread
    const float4* wv = (const float4*)w1;
    float4 bb = ((const float4*)b1)[tc];
    float4 a0 = bb, a1 = bb, a2 = bb, a3 = bb;
    const float4* sv = (const float4*)p1s;
    #pragma unroll 8
    for (int k4 = 0; k4 < 32; ++k4) {
        float4 r0 = sv[(tr*4+0)*D4 + k4];
        float4 r1 = sv[(tr*4+1)*D4 + k4];
        float4 r2 = sv[(tr*4+2)*D4 + k4];
        float4 r3 = sv[(tr*4+3)*D4 + k4];
        float4 wr0 = wv[(k4*4+0)*D4 + tc];
        float4 wr1 = wv[(k4*4+1)*D4 + tc];
        float4 wr2 = wv[(k4*4+2)*D4 + tc];
        float4 wr3 = wv[(k4*4+3)*D4 + tc];
        FMA4(a0, r0.x, wr0) FMA4(a0, r0.y, wr1) FMA4(a0, r0.z, wr2) FMA4(a0, r0.w, wr3)
        FMA4(a1, r1.x, wr0) FMA4(a1, r1.y, wr1) FMA4(a1, r1.z, wr2) FMA4(a1, r1.w, wr3)
        FMA4(a2, r2.x, wr0) FMA4(a2, r2.y, wr1) FMA4(a2, r2.z, wr2) FMA4(a2, r2.w, wr3)
        FMA4(a3, r3.x, wr0) FMA4(a3, r3.y, wr1) FMA4(a3, r3.z, wr2) FMA4(a3, r3.w, wr3)
    }
    (void)acc;
    float4* t1v = (float4*)t1;
    int rowg = b * 32 + tr * 4;
    t1v[(rowg+0)*D4 + tc] = a0;
    t1v[(rowg+1)*D4 + tc] = a1;
    t1v[(rowg+2)*D4 + tc] = a2;
    t1v[(rowg+3)*D4 + tc] = a3;

    float4 s4, q4;
    s4.x = a0.x+a1.x+a2.x+a3.x; s4.y = a0.y+a1.y+a2.y+a3.y;
    s4.z = a0.z+a1.z+a2.z+a3.z; s4.w = a0.w+a1.w+a2.w+a3.w;
    q4.x = a0.x*a0.x+a1.x*a1.x+a2.x*a2.x+a3.x*a3.x;
    q4.y = a0.y*a0.y+a1.y*a1.y+a2.y*a2.y+a3.y*a3.y;
    q4.z = a0.z*a0.z+a1.z*a1.z+a2.z*a2.z+a3.z*a3.z;
    q4.w = a0.w*a0.w+a1.w*a1.w+a2.w*a2.w+a3.w*a3.w;
    *(float4*)&red[0][tr][tc*4] = s4;
    *(float4*)&red[1][tr][tc*4] = q4;
    __syncthreads();
    if (t < D) {
        float S = 0.f, Q = 0.f;
        #pragma unroll
        for (int g = 0; g < 8; ++g) { S += red[0][g][t]; Q += red[1][g][t]; }
        atomicAdd(&statsA[t], S);
        atomicAdd(&statsA[D+t], Q);
    }
}

__global__ __launch_bounds__(256) void k_midF(float* __restrict__ t1,
        const float* __restrict__ w2, const float* __restrict__ b2,
        const float* __restrict__ mg, const float* __restrict__ mb,
        const float* __restrict__ statsA, float* __restrict__ statsB)
{
    __shared__ __align__(16) float ys[32][D];
    __shared__ __align__(16) float red[2][8][D];
    __shared__ __align__(16) float scs[D], shs[D];
    const int t = threadIdx.x;
    const int b = blockIdx.x;
    if (t < D) {
        float m = statsA[t] * (1.f / NL1);
        float v = statsA[D+t] * (1.f / NL1) - m * m;
        float rs = rsqrtf(v + EPSBN);
        float sc = mg[t] * rs;
        scs[t] = sc;
        shs[t] = mb[t] - m * sc;
    }
    __syncthreads();
    const int j4 = t & 31, pr = t >> 5;
    float4 sc4 = *(const float4*)&scs[j4*4];
    float4 sh4 = *(const float4*)&shs[j4*4];
    float4* t1v = (float4*)t1;
    #pragma unroll
    for (int io = 0; io < 4; ++io) {
        int pp = pr + io * 8;
        float4 u = t1v[(b*32 + pp)*D4 + j4];
        float4 y;
        y.x = fmaxf(fmaf(u.x, sc4.x, sh4.x), 0.f);
        y.y = fmaxf(fmaf(u.y, sc4.y, sh4.y), 0.f);
        y.z = fmaxf(fmaf(u.z, sc4.z, sh4.z), 0.f);
        y.w = fmaxf(fmaf(u.w, sc4.w, sh4.w), 0.f);
        *(float4*)&ys[pp][j4*4] = y;
    }
    __syncthreads();
    const int tc = t & 31, tr = t >> 5;
    const float4* wv = (const float4*)w2;
    float4 bb = ((const float4*)b2)[tc];
    float4 a0 = bb, a1 = bb, a2 = bb, a3 = bb;
    const float4* sv = (const float4*)ys;
    #pragma unroll 8
    for (int k4 = 0; k4 < 32; ++k4) {
        float4 r0 = sv[(tr*4+0)*D4 + k4];
        float4 r1 = sv[(tr*4+1)*D4 + k4];
        float4 r2 = sv[(tr*4+2)*D4 + k4];
        float4 r3 = sv[(tr*4+3)*D4 + k4];
        float4 wr0 = wv[(k4*4+0)*D4 + tc];
        float4 wr1 = wv[(k4*4+1)*D4 + tc];
        float4 wr2 = wv[(k4*4+2)*D4 + tc];
        float4 wr3 = wv[(k4*4+3)*D4 + tc];
        FMA4(a0, r0.x, wr0) FMA4(a0, r0.y, wr1) FMA4(a0, r0.z, wr2) FMA4(a0, r0.w, wr3)
        FMA4(a1, r1.x, wr0) FMA4(a1, r1.y, wr1) FMA4(a1, r1.z, wr2) FMA4(a1, r1.w, wr3)
        FMA4(a2, r2.x, wr0) FMA4(a2, r2.y, wr1) FMA4(a2, r2.z, wr2) FMA4(a2, r2.w, wr3)
        FMA4(a3, r3.x, wr0) FMA4(a3, r3.y, wr1) FMA4(a3, r3.z, wr2) FMA4(a3, r3.w, wr3)
    }
    int rowg = b * 32 + tr * 4;
    t1v[(rowg+0)*D4 + tc] = a0;
    t1v[(rowg+1)*D4 + tc] = a1;
    t1v[(rowg+2)*D4 + tc] = a2;
    t1v[(rowg+3)*D4 + tc] = a3;

    float4 s4, q4;
    s4.x = a0.x+a1.x+a2.x+a3.x; s4.y = a0.y+a1.y+a2.y+a3.y;
    s4.z = a0.z+a1.z+a2.z+a3.z; s4.w = a0.w+a1.w+a2.w+a3.w;
    q4.x = a0.x*a0.x+a1.x*a1.x+a2.x*a2.x+a3.x*a3.x;
    q4.y = a0.y*a0.y+a1.y*a1.y+a2.y*a2.y+a3.y*a3.y;
    q4.z = a0.z*a0.z+a1.z*a1.z+a2.z*a2.z+a3.z*a3.z;
    q4.w = a0.w*a0.w+a1.w*a1.w+a2.w*a2.w+a3.w*a3.w;
    *(float4*)&red[0][tr][tc*4] = s4;
    *(float4*)&red[1][tr][tc*4] = q4;
    __syncthreads();
    if (t < D) {
        float S = 0.f, Q = 0.f;
        #pragma unroll
        for (int g = 0; g < 8; ++g) { S += red[0][g][t]; Q += red[1][g][t]; }
        atomicAdd(&statsB[t], S);
        atomicAdd(&statsB[D+t], Q);
    }
}

__global__ __launch_bounds__(256) void k_poolF(const float* __restrict__ t1,
        const float* __restrict__ bg, const float* __restrict__ bb_,
        const float* __restrict__ statsB, float* __restrict__ p2)
{
    __shared__ __align__(16) float red[8][D];
    __shared__ __align__(16) float scs[D], shs[D];
    const int t = threadIdx.x, r = blockIdx.x;
    if (t < D) {
        float m = statsB[t] * (1.f / NL1);
        float v = statsB[D+t] * (1.f / NL1) - m * m;
        float rs = rsqrtf(v + EPSBN);
        float sc = bg[t] * rs;
        scs[t] = sc;
        shs[t] = bb_[t] - m * sc;
    }
    __syncthreads();
    const int j4 = t & 31, rr = t >> 5;
    float4 sc4 = *(const float4*)&scs[j4*4];
    float4 sh4 = *(const float4*)&shs[j4*4];
    const float4* t1v = (const float4*)t1;
    float4 acc = F4Z;
    for (int i = rr; i < 256; i += 8) {
        float4 u = t1v[(r*256 + i)*D4 + j4];
        acc.x += fmaxf(fmaf(u.x, sc4.x, sh4.x), 0.f);
        acc.y += fmaxf(fmaf(u.y, sc4.y, sh4.y), 0.f);
        acc.z += fmaxf(fmaf(u.z, sc4.z, sh4.z), 0.f);
        acc.w += fmaxf(fmaf(u.w, sc4.w, sh4.w), 0.f);
    }
    *(float4*)&red[rr][j4*4] = acc;
    __syncthreads();
    if (t < D) {
        float s = 0.f;
        #pragma unroll
        for (int g = 0; g < 8; ++g) s += red[g][t];
        p2[r*D + t] = s;
    }
}

// ===================== root stage (unchanged, proven) =====================
__global__ __launch_bounds__(256) void k_root1(const float* __restrict__ p2,
        const float* __restrict__ w1, const float* __restrict__ b1,
        float* __restrict__ t2, float* __restrict__ statsC)
{
    __shared__ __align__(16) float ps[8][D];
    __shared__ __align__(16) float red[2][8][D];
    const int t = threadIdx.x, b = blockIdx.x;
    const int j4 = t & 31, rr = t >> 5;
    *(float4*)&ps[rr][j4*4] = ((const float4*)p2)[(b*8 + rr)*D4 + j4];
    __syncthreads();
    const int row = t >> 5, tc = t & 31;
    const float4* wv = (const float4*)w1;
    float4 acc = ((const float4*)b1)[tc];
    #pragma unroll 8
    for (int k4 = 0; k4 < 32; ++k4) {
        float4 a = *(const float4*)&ps[row][k4*4];
        float4 wr0 = wv[(k4*4+0)*D4 + tc];
        float4 wr1 = wv[(k4*4+1)*D4 + tc];
        float4 wr2 = wv[(k4*4+2)*D4 + tc];
        float4 wr3 = wv[(k4*4+3)*D4 + tc];
        FMA4(acc, a.x, wr0) FMA4(acc, a.y, wr1) FMA4(acc, a.z, wr2) FMA4(acc, a.w, wr3)
    }
    ((float4*)t2)[(b*8 + row)*D4 + tc] = acc;
    float4 q;
    q.x = acc.x*acc.x; q.y = acc.y*acc.y; q.z = acc.z*acc.z; q.w = acc.w*acc.w;
    *(float4*)&red[0][row][tc*4] = acc;
    *(float4*)&red[1][row][tc*4] = q;
    __syncthreads();
    if (t < D) {
        float S = 0.f, Q = 0.f;
        #pragma unroll
        for (int g = 0; g < 8; ++g) { S += red[0][g][t]; Q += red[1][g][t]; }
        atomicAdd(&statsC[t], S);
        atomicAdd(&statsC[D+t], Q);
    }
}

__global__ __launch_bounds__(256) void k_root2(float* __restrict__ t2,
        const float* __restrict__ mg, const float* __restrict__ mb,
        const float* __restrict__ statsC,
        const float* __restrict__ w2, const float* __restrict__ b2,
        float* __restrict__ statsD)
{
    __shared__ __align__(16) float ysr[8][D];
    __shared__ __align__(16) float red[2][8][D];
    __shared__ __align__(16) float scs[D], shs[D];
    const int t = threadIdx.x, b = blockIdx.x;
    if (t < D) {
        float m = statsC[t] * (1.f / 256.f);
        float v = statsC[D+t] * (1.f / 256.f) - m * m;
        float rs = rsqrtf(v + EPSBN);
        float sc = mg[t] * rs;
        scs[t] = sc;
        shs[t] = mb[t] - m * sc;
    }
    __syncthreads();
    const int j4 = t & 31, rr = t >> 5;
    {
        float4 u = ((const float4*)t2)[(b*8 + rr)*D4 + j4];
        float4 sc4 = *(const float4*)&scs[j4*4];
        float4 sh4 = *(const float4*)&shs[j4*4];
        float4 y;
        y.x = fmaxf(fmaf(u.x, sc4.x, sh4.x), 0.f);
        y.y = fmaxf(fmaf(u.y, sc4.y, sh4.y), 0.f);
        y.z = fmaxf(fmaf(u.z, sc4.z, sh4.z), 0.f);
        y.w = fmaxf(fmaf(u.w, sc4.w, sh4.w), 0.f);
        *(float4*)&ysr[rr][j4*4] = y;
    }
    __syncthreads();
    const int row = t >> 5, tc = t & 31;
    const float4* wv = (const float4*)w2;
    float4 acc = ((const float4*)b2)[tc];
    #pragma unroll 8
    for (int k4 = 0; k4 < 32; ++k4) {
        float4 a = *(const float4*)&ysr[row][k4*4];
        float4 wr0 = wv[(k4*4+0)*D4 + tc];
        float4 wr1 = wv[(k4*4+1)*D4 + tc];
        float4 wr2 = wv[(k4*4+2)*D4 + tc];
        float4 wr3 = wv[(k4*4+3)*D4 + tc];
        FMA4(acc, a.x, wr0) FMA4(acc, a.y, wr1) FMA4(acc, a.z, wr2) FMA4(acc, a.w, wr3)
    }
    ((float4*)t2)[(b*8 + row)*D4 + tc] = acc;
    float4 q;
    q.x = acc.x*acc.x; q.y = acc.y*acc.y; q.z = acc.z*acc.z; q.w = acc.w*acc.w;
    *(float4*)&red[0][row][tc*4] = acc;
    *(float4*)&red[1][row][tc*4] = q;
    __syncthreads();
    if (t < D) {
        float S = 0.f, Q = 0.f;
        #pragma unroll
        for (int g = 0; g < 8; ++g) { S += red[0][g][t]; Q += red[1][g][t]; }
        atomicAdd(&statsD[t], S);
        atomicAdd(&statsD[D+t], Q);
    }
}

__global__ __launch_bounds__(128) void k_final(const float* __restrict__ u2,
        const float* __restrict__ statsD,
        const float* __restrict__ bg, const float* __restrict__ bb_,
        const float* __restrict__ g0, const float* __restrict__ p2,
        const float* __restrict__ wp, const float* __restrict__ bp,
        float* __restrict__ out)
{
    __shared__ __align__(16) float reps[3*D];
    const int t = threadIdx.x, tree = blockIdx.x;
    if (t < D) {
        float m = statsD[t] * (1.f / 256.f);
        float v = statsD[D+t] * (1.f / 256.f) - m * m;
        float rs = rsqrtf(v + EPSBN);
        float sc = bg[t] * rs;
        float sh = bb_[t] - m * sc;
        reps[2*D + t] = fmaxf(fmaf(u2[tree*D + t], sc, sh), 0.f);
        reps[t]       = g0[tree*D + t];
        reps[D + t]   = p2[tree*D + t];
    }
    __syncthreads();
    if (t < 32) {
        float acc = bp[t];
        #pragma unroll 8
        for (int j = 0; j < 3*D; ++j) acc = fmaf(reps[j], wp[j*32 + t], acc);
        float mx = acc;
        #pragma unroll
        for (int mk = 16; mk > 0; mk >>= 1) mx = fmaxf(mx, __shfl_xor(mx, mk));
        float e = expf(acc - mx);
        float s = e;
        #pragma unroll
        for (int mk = 16; mk > 0; mk >>= 1) s += __shfl_xor(s, mk);
        out[tree*32 + t] = e / s;
    }
}

extern "C" void kernel_launch(void* const* d_in, const int* in_sizes, int n_in,
                              void* d_out, int out_size, void* d_ws, size_t ws_size,
                              hipStream_t stream)
{
    const float* x    = (const float*)d_in[0];
    const float* m1w1 = (const float*)d_in[5];
    const float* m1b1 = (const float*)d_in[6];
    const float* m1g  = (const float*)d_in[7];
    const float* m1be = (const float*)d_in[8];
    const float* m1w2 = (const float*)d_in[9];
    const float* m1b2 = (const float*)d_in[10];
    const float* bn1g = (const float*)d_in[11];
    const float* bn1b = (const float*)d_in[12];
    const float* m2w1 = (const float*)d_in[13];
    const float* m2b1 = (const float*)d_in[14];
    const float* m2g  = (const float*)d_in[15];
    const float* m2be = (const float*)d_in[16];
    const float* m2w2 = (const float*)d_in[17];
    const float* m2b2 = (const float*)d_in[18];
    const float* bn2g = (const float*)d_in[19];
    const float* bn2b = (const float*)d_in[20];
    const float* wp   = (const float*)d_in[21];
    const float* bp   = (const float*)d_in[22];
    float* out = (float*)d_out;
    float* ws  = (float*)d_ws;

    float* g0 = ws + G0_OFF;
    float* p2 = ws + P2_OFF;
    float* sA = ws + SA_OFF;
    float* sB = ws + SB_OFF;
    float* sC = ws + SC_OFF;
    float* sD = ws + SD_OFF;
    float* t2 = ws + T2_OFF;
    float* t1 = ws + T1F_OFF;

    hipLaunchKernelGGL(k_zero, dim3(260), dim3(256), 0, stream, ws);

    void* args[] = { (void*)&x, (void*)&m1w1, (void*)&m1b1, (void*)&m1g, (void*)&m1be,
                     (void*)&m1w2, (void*)&m1b2, (void*)&bn1g, (void*)&bn1b,
                     (void*)&g0, (void*)&p2, (void*)&sA, (void*)&sB };
    hipError_t ce = hipLaunchCooperativeKernel((void*)k_fused, dim3(256), dim3(512),
                                               args, 0, stream);
    if (ce != hipSuccess) {
        // diagnostic fallback: proven split-kernel path (visible in rocprof names)
        hipLaunchKernelGGL(k_leafF, dim3(2048), dim3(256), 0, stream, x, m1w1, m1b1, t1, g0, sA);
        hipLaunchKernelGGL(k_midF,  dim3(2048), dim3(256), 0, stream, t1, m1w2, m1b2, m1g, m1be, sA, sB);
        hipLaunchKernelGGL(k_poolF, dim3(256),  dim3(256), 0, stream, t1, bn1g, bn1b, sB, p2);
    }

    hipLaunchKernelGGL(k_root1, dim3(32),  dim3(256), 0, stream, p2, m2w1, m2b1, t2, sC);
    hipLaunchKernelGGL(k_root2, dim3(32),  dim3(256), 0, stream, t2, m2g, m2be, sC, m2w2, m2b2, sD);
    hipLaunchKernelGGL(k_final, dim3(256), dim3(128), 0, stream, t2, sD, bn2g, bn2b, g0, p2, wp, bp, out);
}